// Round 1
// 2953.821 us; speedup vs baseline: 1.1223x; 1.1223x over previous
//
#include <hip/hip_runtime.h>
#include <math.h>

#define BT 64
#define CH 256
#define HW 4096
#define AL 32
#define SCALE 0.0625f   // 256^-0.5

typedef unsigned short ushort_t;
typedef __bf16 bf16x8 __attribute__((ext_vector_type(8)));
typedef short  short8 __attribute__((ext_vector_type(8)));
typedef float  f32x4  __attribute__((ext_vector_type(4)));

__device__ __forceinline__ float gelu_f(float x){
    return 0.5f*x*(1.0f+erff(x*0.70710678118654752f));
}
__device__ __forceinline__ ushort_t f2bf(float f){
    unsigned int u = __builtin_bit_cast(unsigned int, f);
    u += 0x7fffu + ((u>>16)&1u);
    return (ushort_t)(u>>16);
}
__device__ __forceinline__ float bf2f(ushort_t h){
    unsigned int u = ((unsigned int)h)<<16;
    return __builtin_bit_cast(float, u);
}

#define GLOAD_LDS16(gp, lp) __builtin_amdgcn_global_load_lds( \
    (const __attribute__((address_space(1))) unsigned int*)(gp), \
    (__attribute__((address_space(3))) unsigned int*)(lp), 16, 0, 0)

// ---------------------------------------------------------------------------
// bf16 MFMA GEMM: Out[b][o][p] = epi(sum_c W[o][c]*Xt[b][p][c] + bias[o])
// EPI: 0=none 1=gelu 2=relu 3=gate: Out = E1 + tanh(v)*E2
// TOUT: 0=fp32 [o][p] ; 1=bf16 transposed [p][o] ; 2=both (fp32 [o][p] + bf16 [p][o])
// WSTAT: accumulate per-(b,o) {sum, sumsq} of post-bias values into St (pre-zeroed)
template<int EPI, int TOUT, int WSTAT>
__global__ __launch_bounds__(256,2)
void gemm_mfma_kernel(const ushort_t* __restrict__ Wb, const float* __restrict__ bias,
                      const ushort_t* __restrict__ Xt, float* __restrict__ Out,
                      ushort_t* __restrict__ OutB,
                      const float* __restrict__ E1, const float* __restrict__ E2,
                      float* __restrict__ St)
{
    __shared__ ushort_t sW[128*32];
    __shared__ ushort_t sX[128*32];
    const int b  = blockIdx.z;
    const int o0 = blockIdx.y*128, p0 = blockIdx.x*128;
    const int tid = threadIdx.x, lane = tid & 63, w = tid >> 6;
    const int wm = w >> 1, wn = w & 1;
    const int rr = lane >> 2;          // 0..15
    const int kk8 = (lane & 3) * 8;

    f32x4 acc[4][4] = {};

    for (int k0 = 0; k0 < CH; k0 += 32) {
        #pragma unroll
        for (int j = 0; j < 2; ++j) {
            const ushort_t* gw = Wb + (size_t)(o0 + w*32 + j*16 + rr)*CH + k0 + kk8;
            GLOAD_LDS16(gw, sW + (size_t)w*1024 + j*512);
        }
        #pragma unroll
        for (int j = 0; j < 2; ++j) {
            const ushort_t* gx = Xt + ((size_t)b*HW + p0 + w*32 + j*16 + rr)*CH + k0 + kk8;
            GLOAD_LDS16(gx, sX + (size_t)w*1024 + j*512);
        }
        __syncthreads();
        bf16x8 af[4], bfr[4];
        #pragma unroll
        for (int mt = 0; mt < 4; ++mt) {
            short8 raw = *(const short8*)(sW + (size_t)(wm*64 + mt*16 + (lane&15))*32 + (lane>>4)*8);
            af[mt] = __builtin_bit_cast(bf16x8, raw);
        }
        #pragma unroll
        for (int nt = 0; nt < 4; ++nt) {
            short8 raw = *(const short8*)(sX + (size_t)(wn*64 + nt*16 + (lane&15))*32 + (lane>>4)*8);
            bfr[nt] = __builtin_bit_cast(bf16x8, raw);
        }
        #pragma unroll
        for (int mt = 0; mt < 4; ++mt)
            #pragma unroll
            for (int nt = 0; nt < 4; ++nt)
                acc[mt][nt] = __builtin_amdgcn_mfma_f32_16x16x32_bf16(af[mt], bfr[nt], acc[mt][nt], 0, 0, 0);
        __syncthreads();
    }

    const int pcol = lane & 15, quad = lane >> 4;
    const size_t obase = (size_t)b*CH*HW;
    if (TOUT == 0) {
        #pragma unroll
        for (int mt = 0; mt < 4; ++mt) {
            #pragma unroll
            for (int r = 0; r < 4; ++r) {
                const int o = o0 + wm*64 + mt*16 + quad*4 + r;
                const float bv = bias ? bias[o] : 0.0f;
                #pragma unroll
                for (int nt = 0; nt < 4; ++nt) {
                    const int p = p0 + wn*64 + nt*16 + pcol;
                    float v = acc[mt][nt][r] + bv;
                    if (EPI == 1) v = gelu_f(v);
                    if (EPI == 2) v = fmaxf(v, 0.0f);
                    if (EPI == 3) {
                        const size_t idx = obase + (size_t)o*HW + p;
                        v = E1[idx] + tanhf(v)*E2[idx];
                    }
                    Out[obase + (size_t)o*HW + p] = v;
                }
            }
        }
    } else if (TOUT == 1) {
        #pragma unroll
        for (int mt = 0; mt < 4; ++mt) {
            const int ob = o0 + wm*64 + mt*16 + quad*4;
            #pragma unroll
            for (int nt = 0; nt < 4; ++nt) {
                const int p = p0 + wn*64 + nt*16 + pcol;
                ushort4 u;
                float v0 = acc[mt][nt][0] + (bias ? bias[ob+0] : 0.f);
                float v1 = acc[mt][nt][1] + (bias ? bias[ob+1] : 0.f);
                float v2 = acc[mt][nt][2] + (bias ? bias[ob+2] : 0.f);
                float v3 = acc[mt][nt][3] + (bias ? bias[ob+3] : 0.f);
                if (EPI == 1) { v0=gelu_f(v0); v1=gelu_f(v1); v2=gelu_f(v2); v3=gelu_f(v3); }
                if (EPI == 2) { v0=fmaxf(v0,0.f); v1=fmaxf(v1,0.f); v2=fmaxf(v2,0.f); v3=fmaxf(v3,0.f); }
                u.x=f2bf(v0); u.y=f2bf(v1); u.z=f2bf(v2); u.w=f2bf(v3);
                *(ushort4*)(OutB + ((size_t)b*HW + p)*CH + ob) = u;
            }
        }
    } else {  // TOUT == 2: dual write fp32 [o][p] + bf16 [p][o]
        #pragma unroll
        for (int mt = 0; mt < 4; ++mt) {
            const int ob = o0 + wm*64 + mt*16 + quad*4;
            #pragma unroll
            for (int nt = 0; nt < 4; ++nt) {
                const int p = p0 + wn*64 + nt*16 + pcol;
                float v[4];
                #pragma unroll
                for (int r = 0; r < 4; ++r) {
                    float t = acc[mt][nt][r] + (bias ? bias[ob+r] : 0.f);
                    if (EPI == 1) t = gelu_f(t);
                    if (EPI == 2) t = fmaxf(t, 0.f);
                    v[r] = t;
                    Out[obase + (size_t)(ob+r)*HW + p] = t;
                }
                ushort4 u;
                u.x=f2bf(v[0]); u.y=f2bf(v[1]); u.z=f2bf(v[2]); u.w=f2bf(v[3]);
                *(ushort4*)(OutB + ((size_t)b*HW + p)*CH + ob) = u;
            }
        }
    }

    if (WSTAT) {
        // per-(b,o) partial {sum, sumsq} over this block's 128 p's
        float s1[4][4], s2[4][4];
        #pragma unroll
        for (int mt = 0; mt < 4; ++mt) {
            #pragma unroll
            for (int r = 0; r < 4; ++r) {
                const int o = o0 + wm*64 + mt*16 + quad*4 + r;
                const float bv = bias ? bias[o] : 0.0f;
                float a = 0.f, q = 0.f;
                #pragma unroll
                for (int nt = 0; nt < 4; ++nt) {
                    const float v = acc[mt][nt][r] + bv;
                    a += v; q += v*v;
                }
                #pragma unroll
                for (int off = 1; off < 16; off <<= 1) {
                    a += __shfl_xor(a, off);
                    q += __shfl_xor(q, off);
                }
                s1[mt][r] = a; s2[mt][r] = q;
            }
        }
        float* red = (float*)sW;  // 128*2 floats, LDS reuse
        __syncthreads();
        if (wn == 0 && pcol == 0) {
            #pragma unroll
            for (int mt = 0; mt < 4; ++mt)
                #pragma unroll
                for (int r = 0; r < 4; ++r) {
                    const int ol = wm*64 + mt*16 + quad*4 + r;
                    red[ol*2] = s1[mt][r]; red[ol*2+1] = s2[mt][r];
                }
        }
        __syncthreads();
        if (wn == 1 && pcol == 0) {
            #pragma unroll
            for (int mt = 0; mt < 4; ++mt)
                #pragma unroll
                for (int r = 0; r < 4; ++r) {
                    const int ol = wm*64 + mt*16 + quad*4 + r;
                    const int o = o0 + ol;
                    atomicAdd(&St[((size_t)b*CH + o)*2],   red[ol*2]   + s1[mt][r]);
                    atomicAdd(&St[((size_t)b*CH + o)*2+1], red[ol*2+1] + s2[mt][r]);
                }
        }
    }
}

// ---------------------------------------------------------------------------
__global__ __launch_bounds__(256)
void zero_kernel(float* __restrict__ p)
{
    p[blockIdx.x*256 + threadIdx.x] = 0.f;
}

// St[row*2..+1] = {sum,sumsq} -> {mean, rstd}, in place. grid(BT*CH/256).
__global__ __launch_bounds__(256)
void stats_finalize_kernel(float* __restrict__ St)
{
    const int row = blockIdx.x*256 + threadIdx.x;
    const float s1 = St[(size_t)row*2], s2 = St[(size_t)row*2+1];
    const float mean = s1 * (1.0f/HW);
    const float var  = s2 * (1.0f/HW) - mean*mean;
    St[(size_t)row*2]   = mean;
    St[(size_t)row*2+1] = rsqrtf(var + 1e-5f);
}

// ---------------------------------------------------------------------------
// Transpose-convert: Xa fp32 [b][c][p] -> Out bf16 [b][p][c].
// MODE 0: plain. MODE 1: normalize (St {mean,rstd} per b,c) at load.
// MODE 2: normalize at load + multiply by Mul bf16 [b][p][c] at store.
template<int MODE>
__global__ __launch_bounds__(256)
void transpose_bf16_kernel(const float* __restrict__ Xa, const ushort_t* __restrict__ Mul,
                           const float* __restrict__ St, ushort_t* __restrict__ Out)
{
    __shared__ float sT[32][33];
    const int b = blockIdx.z, c0 = blockIdx.y*32, p0 = blockIdx.x*32;
    const int tid = threadIdx.x;
    {
        const int cr = tid >> 3, pq = (tid & 7)*4;
        float4 v = *(const float4*)(Xa + ((size_t)b*CH + c0 + cr)*HW + p0 + pq);
        if (MODE >= 1) {
            const float m = St[((size_t)b*CH + c0 + cr)*2];
            const float r = St[((size_t)b*CH + c0 + cr)*2+1];
            v.x = (v.x-m)*r; v.y = (v.y-m)*r; v.z = (v.z-m)*r; v.w = (v.w-m)*r;
        }
        sT[cr][pq+0]=v.x; sT[cr][pq+1]=v.y; sT[cr][pq+2]=v.z; sT[cr][pq+3]=v.w;
    }
    __syncthreads();
    {
        const int pr = tid >> 3, cq = (tid & 7)*4;
        const size_t oidx = ((size_t)b*HW + p0 + pr)*CH + c0 + cq;
        float v0 = sT[cq+0][pr], v1 = sT[cq+1][pr], v2 = sT[cq+2][pr], v3 = sT[cq+3][pr];
        if (MODE == 2) {
            const ushort4 m = *(const ushort4*)(Mul + oidx);
            v0 *= bf2f(m.x); v1 *= bf2f(m.y); v2 *= bf2f(m.z); v3 *= bf2f(m.w);
        }
        ushort4 u; u.x=f2bf(v0); u.y=f2bf(v1); u.z=f2bf(v2); u.w=f2bf(v3);
        *(ushort4*)(Out + oidx) = u;
    }
}

// ---------------------------------------------------------------------------
__global__ __launch_bounds__(256)
void wconv_kernel(const float* w0, const float* w1, const float* w2, const float* w3,
                  const float* w4, const float* w5, const float* w6, const float* w7,
                  const float* w8, ushort_t* __restrict__ Wb)
{
    const float* src;
    switch (blockIdx.y) {
        case 0: src=w0; break; case 1: src=w1; break; case 2: src=w2; break;
        case 3: src=w3; break; case 4: src=w4; break; case 5: src=w5; break;
        case 6: src=w6; break; case 7: src=w7; break; default: src=w8; break;
    }
    const int i = (blockIdx.x*256 + threadIdx.x)*4;
    const float4 v = *(const float4*)(src + i);
    ushort4 u; u.x=f2bf(v.x); u.y=f2bf(v.y); u.z=f2bf(v.z); u.w=f2bf(v.w);
    *(ushort4*)(Wb + (size_t)blockIdx.y*65536 + i) = u;
}

// ---------------------------------------------------------------------------
// Pointwise conv over audio length L.
// EPI: 0=none, 1=*mask, 2=Resid + gelu(v), 4=*mask*rstd*SCALE (St per b,o)
// TR : 0 -> Out [b][o][l] ; 1 -> Out [b][l][o]
template<int EPI, int TR>
__global__ __launch_bounds__(256)
void conv_l_kernel(const float* __restrict__ W, const float* __restrict__ bias,
                   const float* __restrict__ X, float* __restrict__ Out,
                   const float* __restrict__ Mask, const float* __restrict__ Resid,
                   const float* __restrict__ St)
{
    const int b = blockIdx.x;
    const int o = blockIdx.y*8 + (threadIdx.x>>5);
    const int l = threadIdx.x & 31;
    const float* xb = X + (size_t)b*CH*AL + l;
    const float* wr = W + (size_t)o*CH;
    float acc = bias ? bias[o] : 0.0f;
    #pragma unroll 8
    for (int c=0;c<CH;++c) acc = fmaf(wr[c], xb[(size_t)c*AL], acc);
    if (EPI==1) acc *= Mask[b*AL + l];
    if (EPI==4) acc *= Mask[b*AL + l] * St[((size_t)b*CH + o)*2+1] * SCALE;
    if (EPI==2) {
        const size_t oi = (size_t)b*CH*AL + (size_t)o*AL + l;
        acc = Resid[oi] + gelu_f(acc);
    }
    if (TR == 0) Out[(size_t)b*CH*AL + (size_t)o*AL + l] = acc;
    else         Out[((size_t)b*AL + l)*CH + o] = acc;
}

// ---------------------------------------------------------------------------
// lbias[b][l] = -sum_c mean_q[b][c] * Kn[b][c][l]   (Kn already has rstd*SCALE*mask)
__global__ __launch_bounds__(256)
void lbias_kernel(const float* __restrict__ Kn, const float* __restrict__ St,
                  float* __restrict__ Lb)
{
    const int b = blockIdx.x, tid = threadIdx.x;
    const int l = tid & 31, g = tid >> 5;
    float s = 0.f;
    #pragma unroll 8
    for (int cc=0; cc<32; ++cc){
        const int c = g*32 + cc;
        s += St[((size_t)b*CH + c)*2] * Kn[((size_t)b*CH + c)*AL + l];
    }
    __shared__ float red[8][32];
    red[g][l] = s;
    __syncthreads();
    if (tid < 32){
        float t = 0.f;
        #pragma unroll
        for (int gg=0; gg<8; ++gg) t += red[gg][tid];
        Lb[b*AL + tid] = -t;
    }
}

// ---------------------------------------------------------------------------
// Visual attention, register-tiled, 128 tokens/block.
// Q raw fp32 [b][c][p] (norm folded into Kn + Lb). Kn fp32 [b][c][l].
// AVt fp32 [b][l][c]. Output bf16 [b][p][c].
__device__ __forceinline__ void attn_loadq(f32x4 (&dst)[8], const float* Qb, int kc){
    #pragma unroll
    for (int kk=0;kk<8;++kk)
        dst[kk] = *(const f32x4*)(Qb + (size_t)(kc*8+kk)*HW);
}
__device__ __forceinline__ void attn_fma(float (&s)[4][4], const f32x4 (&q)[8],
                                         const float* sKV, int kc, int lq){
    #pragma unroll
    for (int kk=0;kk<8;++kk){
        const f32x4 kv = *(const f32x4*)&sKV[(kc*8+kk)*32 + lq*4];
        #pragma unroll
        for (int i=0;i<4;++i)
            #pragma unroll
            for (int j=0;j<4;++j)
                s[i][j] = fmaf(q[kk][i], kv[j], s[i][j]);
    }
}

__global__ __launch_bounds__(256,3)
void attn_v_kernel(const float* __restrict__ Q, const float* __restrict__ Kn,
                   const float* __restrict__ AVt, const float* __restrict__ Lb,
                   const float* __restrict__ Mask, ushort_t* __restrict__ OutB)
{
    __shared__ float sKV[8192];      // Kn [256][32], later AVt [32][256]
    __shared__ float sP[32*128];     // scores / probs [l][p]
    __shared__ float sBias[32];
    const int b  = blockIdx.y;
    const int p0 = blockIdx.x * 128;
    const int tid = threadIdx.x;
    const int pg = tid >> 3;         // 0..31 -> 4 tokens each (wave-disjoint)
    const int lq = tid & 7;          // 0..7  -> 4 l's each

    // stage Kn (32 KB, linear)
    #pragma unroll
    for (int ii=0; ii<8; ++ii){
        const int fi = ii*256 + tid;
        *(f32x4*)&sKV[fi*4] = *(const f32x4*)(Kn + (size_t)b*CH*AL + (size_t)fi*4);
    }
    if (tid < 32) sBias[tid] = Lb[b*AL + tid] + 10000.f*Mask[b*AL + tid] - 10000.f;
    __syncthreads();

    // ---- QK^T: s[i][j] = sum_c Q[c][p0+pg*4+i] * Kn[c][lq*4+j] ----
    const float* Qb = Q + (size_t)b*CH*HW + p0 + pg*4;
    float s[4][4] = {};
    {
        f32x4 qa[8], qb2[8];
        attn_loadq(qa, Qb, 0);
        for (int kc = 0; kc < 32; kc += 2){
            attn_loadq(qb2, Qb, kc+1);
            attn_fma(s, qa, sKV, kc, lq);
            if (kc+2 < 32) attn_loadq(qa, Qb, kc+2);
            attn_fma(s, qb2, sKV, kc+1, lq);
        }
    }
    __syncthreads();   // all QK reads of sKV done

    // write raw scores, and restage AVt over the Kn region
    #pragma unroll
    for (int j=0;j<4;++j)
        *(f32x4*)&sP[(lq*4+j)*128 + pg*4] = (f32x4){s[0][j], s[1][j], s[2][j], s[3][j]};
    #pragma unroll
    for (int ii=0; ii<8; ++ii){
        const int fi = ii*256 + tid;
        *(f32x4*)&sKV[fi*4] = *(const f32x4*)(AVt + (size_t)b*AL*CH + (size_t)fi*4);
    }
    __syncthreads();

    // ---- softmax over l (row p owned by thread pair tid, tid^1) ----
    {
        const int p = tid >> 1, lh = tid & 1;
        float v[16];
        #pragma unroll
        for (int jj=0;jj<16;++jj) v[jj] = sP[(lh*16+jj)*128 + p] + sBias[lh*16+jj];
        float m = v[0];
        #pragma unroll
        for (int jj=1;jj<16;++jj) m = fmaxf(m, v[jj]);
        m = fmaxf(m, __shfl_xor(m, 1));
        float z = 0.f;
        #pragma unroll
        for (int jj=0;jj<16;++jj){ v[jj] = expf(v[jj]-m); z += v[jj]; }
        z += __shfl_xor(z, 1);
        const float rz = 1.f/z;
        #pragma unroll
        for (int jj=0;jj<16;++jj) sP[(lh*16+jj)*128 + p] = v[jj]*rz;
    }
    __syncthreads();

    // ---- PV: out[p][c] = sum_l P[l][p] * AVt[l][c], bf16 [p][c] stores ----
    const int cg = lq;  // 0..7 -> 8 channels per 64-ch chunk
    ushort_t* Ob = OutB + ((size_t)b*HW + p0 + pg*4)*CH;
    #pragma unroll 1
    for (int c0=0; c0<CH; c0+=64){
        float acc[4][8] = {};
        #pragma unroll
        for (int k=0;k<32;++k){
            const f32x4 pv = *(const f32x4*)&sP[k*128 + pg*4];
            const f32x4 a0 = *(const f32x4*)&sKV[k*256 + c0 + cg*8];
            const f32x4 a1 = *(const f32x4*)&sKV[k*256 + c0 + cg*8 + 4];
            #pragma unroll
            for (int i=0;i<4;++i){
                acc[i][0]=fmaf(pv[i],a0[0],acc[i][0]); acc[i][1]=fmaf(pv[i],a0[1],acc[i][1]);
                acc[i][2]=fmaf(pv[i],a0[2],acc[i][2]); acc[i][3]=fmaf(pv[i],a0[3],acc[i][3]);
                acc[i][4]=fmaf(pv[i],a1[0],acc[i][4]); acc[i][5]=fmaf(pv[i],a1[1],acc[i][5]);
                acc[i][6]=fmaf(pv[i],a1[2],acc[i][6]); acc[i][7]=fmaf(pv[i],a1[3],acc[i][7]);
            }
        }
        #pragma unroll
        for (int i=0;i<4;++i){
            short8 u;
            #pragma unroll
            for (int j=0;j<8;++j) u[j] = (short)f2bf(acc[i][j]);
            *(short8*)(Ob + (size_t)i*CH + c0 + cg*8) = u;
        }
    }
}

// ---------------------------------------------------------------------------
// Audio attention, phase 1: raw scores (rstd_ak folded into sAQ; mean term
// is constant over the softmax axis p and cancels).
__global__ __launch_bounds__(256)
void sima_raw_kernel(const float* __restrict__ AQ, const float* __restrict__ AK,
                     const float* __restrict__ Mask, const float* __restrict__ St,
                     float* __restrict__ Sraw)
{
    __shared__ float sAQ[CH*AL];
    const int b = blockIdx.y;
    const int p = blockIdx.x*256 + threadIdx.x;
    const int tid = threadIdx.x;
    #pragma unroll
    for (int i=0;i<32;++i){
        const int idx = tid + 256*i;
        sAQ[idx] = AQ[(size_t)b*CH*AL + idx] * Mask[b*AL + (idx&31)] * SCALE
                 * St[((size_t)b*CH + (idx>>5))*2+1];
    }
    __syncthreads();
    float s[32];
    #pragma unroll
    for (int l=0;l<32;++l) s[l]=0.f;
    const float* akb = AK + (size_t)b*CH*HW + p;
    for (int c=0;c<CH;++c){
        const float a = akb[(size_t)c*HW];
        const float* qr = &sAQ[c*32];
        #pragma unroll
        for (int l=0;l<32;++l) s[l] = fmaf(qr[l], a, s[l]);
    }
    float* outp = Sraw + (size_t)b*AL*HW + p;
    #pragma unroll
    for (int l=0;l<32;++l) outp[(size_t)l*HW] = s[l];
}

// Phase 2: per-(b,l) softmax stats over HW.
__global__ __launch_bounds__(256)
void sima_stats_kernel(const float* __restrict__ Sraw, float2* __restrict__ Stats)
{
    const size_t base = (size_t)blockIdx.x * HW;
    const int tid = threadIdx.x;
    float v[16];
    #pragma unroll
    for (int i=0;i<4;++i){
        const float4 t = *(const float4*)(Sraw + base + tid*4 + i*1024);
        v[i*4+0]=t.x; v[i*4+1]=t.y; v[i*4+2]=t.z; v[i*4+3]=t.w;
    }
    float m = v[0];
    #pragma unroll
    for (int i=1;i<16;++i) m = fmaxf(m, v[i]);
    #pragma unroll
    for (int off=1; off<64; off<<=1) m = fmaxf(m, __shfl_xor(m, off));
    __shared__ float rm[4], rz[4];
    if ((tid&63)==0) rm[tid>>6]=m;
    __syncthreads();
    m = fmaxf(fmaxf(rm[0],rm[1]), fmaxf(rm[2],rm[3]));
    float z=0.f;
    #pragma unroll
    for (int i=0;i<16;++i) z += expf(v[i]-m);
    #pragma unroll
    for (int off=1; off<64; off<<=1) z += __shfl_xor(z, off);
    if ((tid&63)==0) rz[tid>>6]=z;
    __syncthreads();
    if (tid==0) Stats[blockIdx.x] = make_float2(m, 1.0f/(rz[0]+rz[1]+rz[2]+rz[3]));
}

// Phase 3: AO[b][c][l] = (sum_p P[l][p]*VV[b][c][p] - mean_vv[c]) * rstd_vv[c]
// (uses sum_p P = 1 to fold the InstanceNorm of VV into the epilogue).
__global__ __launch_bounds__(256)
void sima_pv_kernel(const float* __restrict__ Sraw, const float2* __restrict__ SmStats,
                    const float* __restrict__ VV, const float* __restrict__ ChSt,
                    float* __restrict__ AO)
{
    __shared__ float sA[32*33];
    __shared__ float sB[64*36];
    __shared__ float sM[32], sR[32];
    const int b  = blockIdx.x >> 2;
    const int c0 = (blockIdx.x & 3) * 64;
    const int tid = threadIdx.x;
    if (tid < 32){
        const float2 st = SmStats[b*AL + tid];
        sM[tid] = st.x; sR[tid] = st.y;
    }
    __syncthreads();
    const int lh = tid & 15;
    const int cq = tid >> 4;
    const int lr = tid >> 3, k4 = (tid & 7) * 4;
    float acc[2][4] = {{0.f,0.f,0.f,0.f},{0.f,0.f,0.f,0.f}};
    for (int p0=0; p0<HW; p0+=32){
        {
            const float4 t = *(const float4*)(Sraw + ((size_t)b*AL + lr)*HW + p0 + k4);
            const float mm = sM[lr], rr2 = sR[lr];
            sA[lr*33 + k4+0] = expf(t.x-mm)*rr2;
            sA[lr*33 + k4+1] = expf(t.y-mm)*rr2;
            sA[lr*33 + k4+2] = expf(t.z-mm)*rr2;
            sA[lr*33 + k4+3] = expf(t.w-mm)*rr2;
        }
        #pragma unroll
        for (int i=0;i<2;++i){
            const int cc = (tid>>3) + 32*i;
            *(float4*)&sB[cc*36 + k4] = *(const float4*)(VV + ((size_t)b*CH + c0 + cc)*HW + p0 + k4);
        }
        __syncthreads();
        #pragma unroll
        for (int kk=0;kk<32;++kk){
            const float a0 = sA[lh*33 + kk];
            const float a1 = sA[(lh+16)*33 + kk];
            #pragma unroll
            for (int j=0;j<4;++j){
                const float bb = sB[(cq*4+j)*36 + kk];
                acc[0][j] = fmaf(a0, bb, acc[0][j]);
                acc[1][j] = fmaf(a1, bb, acc[1][j]);
            }
        }
        __syncthreads();
    }
    #pragma unroll
    for (int j=0;j<4;++j){
        const int c = c0 + cq*4 + j;
        const float m0 = ChSt[((size_t)b*CH + c)*2];
        const float r0 = ChSt[((size_t)b*CH + c)*2+1];
        AO[((size_t)b*CH + c)*AL + lh]      = (acc[0][j]-m0)*r0;
        AO[((size_t)b*CH + c)*AL + lh + 16] = (acc[1][j]-m0)*r0;
    }
}

// ---------------------------------------------------------------------------
extern "C" void kernel_launch(void* const* d_in, const int* in_sizes, int n_in,
                              void* d_out, int out_size, void* d_ws, size_t ws_size,
                              hipStream_t stream)
{
    (void)in_sizes; (void)n_in; (void)out_size; (void)ws_size;
    const float* x     = (const float*)d_in[0];
    const float* audio = (const float*)d_in[1];
    const float* amask = (const float*)d_in[2];
    const float* vis_project_w = (const float*)d_in[3];
    const float* vis_project_b = (const float*)d_in[4];
    const float* av_w = (const float*)d_in[5];
    const float* av_b = (const float*)d_in[6];
    const float* vv_w = (const float*)d_in[7];
    const float* vv_b = (const float*)d_in[8];
    const float* vo_w = (const float*)d_in[9];
    const float* vo_b = (const float*)d_in[10];
    const float* ao_w = (const float*)d_in[11];
    const float* ao_b = (const float*)d_in[12];
    const float* vs_key_w = (const float*)d_in[13];
    const float* vs_key_b = (const float*)d_in[14];
    const float* vs_q1_w = (const float*)d_in[15];
    const float* vs_q1_b = (const float*)d_in[16];
    const float* vs_q2_w = (const float*)d_in[17];
    const float* vs_q2_b = (const float*)d_in[18];
    const float* as_key_w = (const float*)d_in[19];
    const float* as_key_b = (const float*)d_in[20];
    const float* as_q1_w = (const float*)d_in[21];
    const float* as_q1_b = (const float*)d_in[22];
    const float* as_q2_w = (const float*)d_in[23];
    const float* as_q2_b = (const float*)d_in[24];
    const float* outconv_w = (const float*)d_in[25];
    const float* outconv_b = (const float*)d_in[26];
    const float* aoc_w = (const float*)d_in[27];
    const float* aoc_b = (const float*)d_in[28];
    const float* gate_w1 = (const float*)d_in[29];
    const float* gate_w2 = (const float*)d_in[30];

    float* out_x = (float*)d_out;                 // [BT][CH][HW]
    float* out_a = out_x + (size_t)BT*CH*HW;      // [BT][CH][AL]
    float* B     = out_x;                         // fp32 scratch in d_out x-region

    const size_t BIG = (size_t)BT*CH*HW;
    ushort_t* Xt   = (ushort_t*)d_ws;             // bf16 [b][p][c], 128 MiB
    ushort_t* VISB = Xt + BIG;                    // bf16 [b][p][c], 128 MiB
    float*  A     = (float*)(VISB + BIG);         // fp32 [b][c][p], 256 MiB
    float*  SIMA  = A + BIG;                      // fp32 [b][l][p], 32 MiB
    float2* STATS = (float2*)(SIMA + (size_t)BT*AL*HW);
    float*  S0 = (float*)(STATS + BT*AL);         // AVt [b][l][c]
    float*  S1 = S0 + (size_t)BT*CH*AL;           // Kn  [b][c][l]
    float*  S2 = S1 + (size_t)BT*CH*AL;           // aq
    float*  S3 = S2 + (size_t)BT*CH*AL;           // tmp / audio_res
    float*  S4 = S3 + (size_t)BT*CH*AL;           // audio_o
    ushort_t* Wb = (ushort_t*)(S4 + (size_t)BT*CH*AL);  // 9 bf16 weights
    float*  SA = (float*)(Wb + (size_t)9*65536);  // channel stats A (q1 -> q -> vo)
    float*  SB = SA + (size_t)2*BT*CH;            // channel stats B (ak -> vv)
    float*  LB = SB + (size_t)2*BT*CH;            // attn l-bias [b][l]

    dim3 b256(256);
    dim3 gW(64, 9);
    dim3 gL(BT, CH/8);
    dim3 gT(HW/32, CH/32, BT);
    dim3 gG(HW/128, CH/128, BT);
    dim3 gAttnV(HW/128, BT);
    dim3 gSimA(HW/256, BT);
    dim3 gZ(2*BT*CH/256);
    dim3 gF(BT*CH/256);

    #define WSLOT(i) (Wb + (size_t)(i)*65536)
    // slots: 0 vs_q1, 1 as_key, 2 vv, 3 vis_project, 4 vs_q2, 5 vo, 6 outconv, 7 gate_w1, 8 gate_w2
    hipLaunchKernelGGL(wconv_kernel, gW, b256, 0, stream,
                       vs_q1_w, as_key_w, vv_w, vis_project_w, vs_q2_w, vo_w, outconv_w, gate_w1, gate_w2, Wb);
    // audio small convs
    hipLaunchKernelGGL((conv_l_kernel<1,1>), gL, b256, 0, stream, av_w, av_b, audio, S0, amask, nullptr, nullptr);
    hipLaunchKernelGGL((conv_l_kernel<0,0>), gL, b256, 0, stream, as_q1_w, as_q1_b, audio, S3, nullptr, nullptr, nullptr);
    hipLaunchKernelGGL((conv_l_kernel<0,0>), gL, b256, 0, stream, as_q2_w, as_q2_b, S3, S2, nullptr, nullptr, nullptr);
    // Xt = T(x)
    hipLaunchKernelGGL((transpose_bf16_kernel<0>), gT, b256, 0, stream, x, nullptr, nullptr, Xt);
    // q1 = conv(vs_q1, x) (raw) + stats
    hipLaunchKernelGGL(zero_kernel, gZ, b256, 0, stream, SA);
    hipLaunchKernelGGL((gemm_mfma_kernel<0,0,1>), gG, b256, 0, stream, WSLOT(0), vs_q1_b, Xt, A, nullptr, nullptr, nullptr, SA);
    hipLaunchKernelGGL(stats_finalize_kernel, gF, b256, 0, stream, SA);
    // ak = conv(as_key, x) (raw) + stats
    hipLaunchKernelGGL(zero_kernel, gZ, b256, 0, stream, SB);
    hipLaunchKernelGGL((gemm_mfma_kernel<0,0,1>), gG, b256, 0, stream, WSLOT(1), as_key_b, Xt, B, nullptr, nullptr, nullptr, SB);
    hipLaunchKernelGGL(stats_finalize_kernel, gF, b256, 0, stream, SB);
    hipLaunchKernelGGL(sima_raw_kernel, gSimA, b256, 0, stream, S2, B, amask, SB, SIMA);
    hipLaunchKernelGGL(sima_stats_kernel, dim3(BT*AL), b256, 0, stream, SIMA, STATS);
    // vv = conv(vv, x) (raw) + stats
    hipLaunchKernelGGL(zero_kernel, gZ, b256, 0, stream, SB);
    hipLaunchKernelGGL((gemm_mfma_kernel<0,0,1>), gG, b256, 0, stream, WSLOT(2), vv_b, Xt, B, nullptr, nullptr, nullptr, SB);
    hipLaunchKernelGGL(stats_finalize_kernel, gF, b256, 0, stream, SB);
    hipLaunchKernelGGL(sima_pv_kernel, dim3(BT*4), b256, 0, stream, SIMA, STATS, B, SB, S4);
    hipLaunchKernelGGL((conv_l_kernel<0,0>), gL, b256, 0, stream, ao_w, ao_b, S4, S3, nullptr, nullptr, nullptr);
    hipLaunchKernelGGL((conv_l_kernel<2,0>), gL, b256, 0, stream, aoc_w, aoc_b, S3, out_a, nullptr, audio, nullptr);
    // vis = gelu(conv(vis_project, x)) -> VISB (bf16 tokens)
    hipLaunchKernelGGL((gemm_mfma_kernel<1,1,0>), gG, b256, 0, stream, WSLOT(3), vis_project_b, Xt, nullptr, VISB, nullptr, nullptr, nullptr);
    // q1n (normalized via SA) -> Xt
    hipLaunchKernelGGL((transpose_bf16_kernel<1>), gT, b256, 0, stream, A, nullptr, SA, Xt);
    // q = conv(vs_q2, q1n) (raw) + stats
    hipLaunchKernelGGL(zero_kernel, gZ, b256, 0, stream, SA);
    hipLaunchKernelGGL((gemm_mfma_kernel<0,0,1>), gG, b256, 0, stream, WSLOT(4), vs_q2_b, Xt, B, nullptr, nullptr, nullptr, SA);
    hipLaunchKernelGGL(stats_finalize_kernel, gF, b256, 0, stream, SA);
    // Kn = conv(vs_key, audio)*mask*rstd_q*scale ; lbias from mean_q
    hipLaunchKernelGGL((conv_l_kernel<4,0>), gL, b256, 0, stream, vs_key_w, vs_key_b, audio, S1, amask, nullptr, SA);
    hipLaunchKernelGGL(lbias_kernel, dim3(BT), b256, 0, stream, S1, SA, LB);
    // attention -> bf16 tokens in Xt
    hipLaunchKernelGGL(attn_v_kernel, gAttnV, b256, 0, stream, B, S1, S0, LB, amask, Xt);
    // vis_out raw = conv(vo, attn_out) + stats
    hipLaunchKernelGGL(zero_kernel, gZ, b256, 0, stream, SA);
    hipLaunchKernelGGL((gemm_mfma_kernel<0,0,1>), gG, b256, 0, stream, WSLOT(5), vo_b, Xt, B, nullptr, nullptr, nullptr, SA);
    hipLaunchKernelGGL(stats_finalize_kernel, gF, b256, 0, stream, SA);
    // Xt = bf16(norm(vis_out) * vis)
    hipLaunchKernelGGL((transpose_bf16_kernel<2>), gT, b256, 0, stream, B, VISB, SA, Xt);
    // vis2 = gelu(conv(outconv, .)) -> A (fp32) + VISB (bf16 tokens)
    hipLaunchKernelGGL((gemm_mfma_kernel<1,2,0>), gG, b256, 0, stream, WSLOT(6), outconv_b, Xt, A, VISB, nullptr, nullptr, nullptr);
    // gate path: relu(. @ gate_w1) -> Xt (bf16 tokens)
    hipLaunchKernelGGL((gemm_mfma_kernel<2,1,0>), gG, b256, 0, stream, WSLOT(7), nullptr, VISB, nullptr, Xt, nullptr, nullptr, nullptr);
    hipLaunchKernelGGL((gemm_mfma_kernel<3,0,0>), gG, b256, 0, stream, WSLOT(8), nullptr, Xt, out_x, nullptr, x, A, nullptr);
    #undef WSLOT
}

// Round 2
// 2715.549 us; speedup vs baseline: 1.2207x; 1.0877x over previous
//
#include <hip/hip_runtime.h>
#include <math.h>

#define BT 64
#define CH 256
#define HW 4096
#define AL 32
#define SCALE 0.0625f   // 256^-0.5

typedef unsigned short ushort_t;
typedef __bf16 bf16x8 __attribute__((ext_vector_type(8)));
typedef short  short8 __attribute__((ext_vector_type(8)));
typedef float  f32x4  __attribute__((ext_vector_type(4)));

__device__ __forceinline__ float gelu_f(float x){
    return 0.5f*x*(1.0f+erff(x*0.70710678118654752f));
}
__device__ __forceinline__ ushort_t f2bf(float f){
    unsigned int u = __builtin_bit_cast(unsigned int, f);
    u += 0x7fffu + ((u>>16)&1u);
    return (ushort_t)(u>>16);
}
__device__ __forceinline__ float bf2f(ushort_t h){
    unsigned int u = ((unsigned int)h)<<16;
    return __builtin_bit_cast(float, u);
}

#define GLOAD_LDS16(gp, lp) __builtin_amdgcn_global_load_lds( \
    (const __attribute__((address_space(1))) unsigned int*)(gp), \
    (__attribute__((address_space(3))) unsigned int*)(lp), 16, 0, 0)

// ---------------------------------------------------------------------------
// bf16 MFMA GEMM: Out[b][o][p] = epi(sum_c W[o][c]*Xt[b][p][c] + bias[o])
// EPI: 0=none 1=gelu 2=relu 3=gate: Out = E1 + tanh(v)*E2
// TOUT: 0=fp32 [o][p] ; 1=bf16 transposed [p][o] ; 2=both (fp32 [o][p] + bf16 [p][o])
// WSTAT: accumulate per-(b,o) {sum, sumsq} of post-bias values into St (pre-zeroed)
template<int EPI, int TOUT, int WSTAT>
__global__ __launch_bounds__(256,2)
void gemm_mfma_kernel(const ushort_t* __restrict__ Wb, const float* __restrict__ bias,
                      const ushort_t* __restrict__ Xt, float* __restrict__ Out,
                      ushort_t* __restrict__ OutB,
                      const float* __restrict__ E1, const float* __restrict__ E2,
                      float* __restrict__ St)
{
    __shared__ ushort_t sW[128*32];
    __shared__ ushort_t sX[128*32];
    const int b  = blockIdx.z;
    const int o0 = blockIdx.y*128, p0 = blockIdx.x*128;
    const int tid = threadIdx.x, lane = tid & 63, w = tid >> 6;
    const int wm = w >> 1, wn = w & 1;
    const int rr = lane >> 2;          // 0..15
    const int kk8 = (lane & 3) * 8;

    f32x4 acc[4][4] = {};

    for (int k0 = 0; k0 < CH; k0 += 32) {
        #pragma unroll
        for (int j = 0; j < 2; ++j) {
            const ushort_t* gw = Wb + (size_t)(o0 + w*32 + j*16 + rr)*CH + k0 + kk8;
            GLOAD_LDS16(gw, sW + (size_t)w*1024 + j*512);
        }
        #pragma unroll
        for (int j = 0; j < 2; ++j) {
            const ushort_t* gx = Xt + ((size_t)b*HW + p0 + w*32 + j*16 + rr)*CH + k0 + kk8;
            GLOAD_LDS16(gx, sX + (size_t)w*1024 + j*512);
        }
        __syncthreads();
        bf16x8 af[4], bfr[4];
        #pragma unroll
        for (int mt = 0; mt < 4; ++mt) {
            short8 raw = *(const short8*)(sW + (size_t)(wm*64 + mt*16 + (lane&15))*32 + (lane>>4)*8);
            af[mt] = __builtin_bit_cast(bf16x8, raw);
        }
        #pragma unroll
        for (int nt = 0; nt < 4; ++nt) {
            short8 raw = *(const short8*)(sX + (size_t)(wn*64 + nt*16 + (lane&15))*32 + (lane>>4)*8);
            bfr[nt] = __builtin_bit_cast(bf16x8, raw);
        }
        #pragma unroll
        for (int mt = 0; mt < 4; ++mt)
            #pragma unroll
            for (int nt = 0; nt < 4; ++nt)
                acc[mt][nt] = __builtin_amdgcn_mfma_f32_16x16x32_bf16(af[mt], bfr[nt], acc[mt][nt], 0, 0, 0);
        __syncthreads();
    }

    const int pcol = lane & 15, quad = lane >> 4;
    const size_t obase = (size_t)b*CH*HW;
    if (TOUT == 0) {
        #pragma unroll
        for (int mt = 0; mt < 4; ++mt) {
            #pragma unroll
            for (int r = 0; r < 4; ++r) {
                const int o = o0 + wm*64 + mt*16 + quad*4 + r;
                const float bv = bias ? bias[o] : 0.0f;
                #pragma unroll
                for (int nt = 0; nt < 4; ++nt) {
                    const int p = p0 + wn*64 + nt*16 + pcol;
                    float v = acc[mt][nt][r] + bv;
                    if (EPI == 1) v = gelu_f(v);
                    if (EPI == 2) v = fmaxf(v, 0.0f);
                    if (EPI == 3) {
                        const size_t idx = obase + (size_t)o*HW + p;
                        v = E1[idx] + tanhf(v)*E2[idx];
                    }
                    Out[obase + (size_t)o*HW + p] = v;
                }
            }
        }
    } else if (TOUT == 1) {
        #pragma unroll
        for (int mt = 0; mt < 4; ++mt) {
            const int ob = o0 + wm*64 + mt*16 + quad*4;
            #pragma unroll
            for (int nt = 0; nt < 4; ++nt) {
                const int p = p0 + wn*64 + nt*16 + pcol;
                ushort4 u;
                float v0 = acc[mt][nt][0] + (bias ? bias[ob+0] : 0.f);
                float v1 = acc[mt][nt][1] + (bias ? bias[ob+1] : 0.f);
                float v2 = acc[mt][nt][2] + (bias ? bias[ob+2] : 0.f);
                float v3 = acc[mt][nt][3] + (bias ? bias[ob+3] : 0.f);
                if (EPI == 1) { v0=gelu_f(v0); v1=gelu_f(v1); v2=gelu_f(v2); v3=gelu_f(v3); }
                if (EPI == 2) { v0=fmaxf(v0,0.f); v1=fmaxf(v1,0.f); v2=fmaxf(v2,0.f); v3=fmaxf(v3,0.f); }
                u.x=f2bf(v0); u.y=f2bf(v1); u.z=f2bf(v2); u.w=f2bf(v3);
                *(ushort4*)(OutB + ((size_t)b*HW + p)*CH + ob) = u;
            }
        }
    } else {  // TOUT == 2: dual write fp32 [o][p] + bf16 [p][o]
        #pragma unroll
        for (int mt = 0; mt < 4; ++mt) {
            const int ob = o0 + wm*64 + mt*16 + quad*4;
            #pragma unroll
            for (int nt = 0; nt < 4; ++nt) {
                const int p = p0 + wn*64 + nt*16 + pcol;
                float v[4];
                #pragma unroll
                for (int r = 0; r < 4; ++r) {
                    float t = acc[mt][nt][r] + (bias ? bias[ob+r] : 0.f);
                    if (EPI == 1) t = gelu_f(t);
                    if (EPI == 2) t = fmaxf(t, 0.f);
                    v[r] = t;
                    Out[obase + (size_t)(ob+r)*HW + p] = t;
                }
                ushort4 u;
                u.x=f2bf(v[0]); u.y=f2bf(v[1]); u.z=f2bf(v[2]); u.w=f2bf(v[3]);
                *(ushort4*)(OutB + ((size_t)b*HW + p)*CH + ob) = u;
            }
        }
    }

    if (WSTAT) {
        // per-(b,o) partial {sum, sumsq} over this block's 128 p's
        float s1[4][4], s2[4][4];
        #pragma unroll
        for (int mt = 0; mt < 4; ++mt) {
            #pragma unroll
            for (int r = 0; r < 4; ++r) {
                const int o = o0 + wm*64 + mt*16 + quad*4 + r;
                const float bv = bias ? bias[o] : 0.0f;
                float a = 0.f, q = 0.f;
                #pragma unroll
                for (int nt = 0; nt < 4; ++nt) {
                    const float v = acc[mt][nt][r] + bv;
                    a += v; q += v*v;
                }
                #pragma unroll
                for (int off = 1; off < 16; off <<= 1) {
                    a += __shfl_xor(a, off);
                    q += __shfl_xor(q, off);
                }
                s1[mt][r] = a; s2[mt][r] = q;
            }
        }
        float* red = (float*)sW;  // 128*2 floats, LDS reuse
        __syncthreads();
        if (wn == 0 && pcol == 0) {
            #pragma unroll
            for (int mt = 0; mt < 4; ++mt)
                #pragma unroll
                for (int r = 0; r < 4; ++r) {
                    const int ol = wm*64 + mt*16 + quad*4 + r;
                    red[ol*2] = s1[mt][r]; red[ol*2+1] = s2[mt][r];
                }
        }
        __syncthreads();
        if (wn == 1 && pcol == 0) {
            #pragma unroll
            for (int mt = 0; mt < 4; ++mt)
                #pragma unroll
                for (int r = 0; r < 4; ++r) {
                    const int ol = wm*64 + mt*16 + quad*4 + r;
                    const int o = o0 + ol;
                    atomicAdd(&St[((size_t)b*CH + o)*2],   red[ol*2]   + s1[mt][r]);
                    atomicAdd(&St[((size_t)b*CH + o)*2+1], red[ol*2+1] + s2[mt][r]);
                }
        }
    }
}

// ---------------------------------------------------------------------------
__global__ __launch_bounds__(256)
void zero_kernel(float* __restrict__ p)
{
    p[blockIdx.x*256 + threadIdx.x] = 0.f;
}

// St[row*2..+1] = {sum,sumsq} -> {mean, rstd}, in place. grid(BT*CH/256).
__global__ __launch_bounds__(256)
void stats_finalize_kernel(float* __restrict__ St)
{
    const int row = blockIdx.x*256 + threadIdx.x;
    const float s1 = St[(size_t)row*2], s2 = St[(size_t)row*2+1];
    const float mean = s1 * (1.0f/HW);
    const float var  = s2 * (1.0f/HW) - mean*mean;
    St[(size_t)row*2]   = mean;
    St[(size_t)row*2+1] = rsqrtf(var + 1e-5f);
}

// ---------------------------------------------------------------------------
// Transpose-convert: Xa fp32 [b][c][p] -> Out bf16 [b][p][c].
// MODE 0: plain. MODE 1: normalize (St {mean,rstd} per b,c) at load.
// MODE 2: normalize at load + multiply by Mul bf16 [b][p][c] at store.
template<int MODE>
__global__ __launch_bounds__(256)
void transpose_bf16_kernel(const float* __restrict__ Xa, const ushort_t* __restrict__ Mul,
                           const float* __restrict__ St, ushort_t* __restrict__ Out)
{
    __shared__ float sT[32][33];
    const int b = blockIdx.z, c0 = blockIdx.y*32, p0 = blockIdx.x*32;
    const int tid = threadIdx.x;
    {
        const int cr = tid >> 3, pq = (tid & 7)*4;
        float4 v = *(const float4*)(Xa + ((size_t)b*CH + c0 + cr)*HW + p0 + pq);
        if (MODE >= 1) {
            const float m = St[((size_t)b*CH + c0 + cr)*2];
            const float r = St[((size_t)b*CH + c0 + cr)*2+1];
            v.x = (v.x-m)*r; v.y = (v.y-m)*r; v.z = (v.z-m)*r; v.w = (v.w-m)*r;
        }
        sT[cr][pq+0]=v.x; sT[cr][pq+1]=v.y; sT[cr][pq+2]=v.z; sT[cr][pq+3]=v.w;
    }
    __syncthreads();
    {
        const int pr = tid >> 3, cq = (tid & 7)*4;
        const size_t oidx = ((size_t)b*HW + p0 + pr)*CH + c0 + cq;
        float v0 = sT[cq+0][pr], v1 = sT[cq+1][pr], v2 = sT[cq+2][pr], v3 = sT[cq+3][pr];
        if (MODE == 2) {
            const ushort4 m = *(const ushort4*)(Mul + oidx);
            v0 *= bf2f(m.x); v1 *= bf2f(m.y); v2 *= bf2f(m.z); v3 *= bf2f(m.w);
        }
        ushort4 u; u.x=f2bf(v0); u.y=f2bf(v1); u.z=f2bf(v2); u.w=f2bf(v3);
        *(ushort4*)(Out + oidx) = u;
    }
}

// ---------------------------------------------------------------------------
__global__ __launch_bounds__(256)
void wconv_kernel(const float* w0, const float* w1, const float* w2, const float* w3,
                  const float* w4, const float* w5, const float* w6, const float* w7,
                  const float* w8, ushort_t* __restrict__ Wb)
{
    const float* src;
    switch (blockIdx.y) {
        case 0: src=w0; break; case 1: src=w1; break; case 2: src=w2; break;
        case 3: src=w3; break; case 4: src=w4; break; case 5: src=w5; break;
        case 6: src=w6; break; case 7: src=w7; break; default: src=w8; break;
    }
    const int i = (blockIdx.x*256 + threadIdx.x)*4;
    const float4 v = *(const float4*)(src + i);
    ushort4 u; u.x=f2bf(v.x); u.y=f2bf(v.y); u.z=f2bf(v.z); u.w=f2bf(v.w);
    *(ushort4*)(Wb + (size_t)blockIdx.y*65536 + i) = u;
}

// ---------------------------------------------------------------------------
// Pointwise conv over audio length L.
// EPI: 0=none, 1=*mask, 2=Resid + gelu(v), 4=*mask*rstd*SCALE (St per b,o)
// TR : 0 -> Out [b][o][l] ; 1 -> Out [b][l][o]
template<int EPI, int TR>
__global__ __launch_bounds__(256)
void conv_l_kernel(const float* __restrict__ W, const float* __restrict__ bias,
                   const float* __restrict__ X, float* __restrict__ Out,
                   const float* __restrict__ Mask, const float* __restrict__ Resid,
                   const float* __restrict__ St)
{
    const int b = blockIdx.x;
    const int o = blockIdx.y*8 + (threadIdx.x>>5);
    const int l = threadIdx.x & 31;
    const float* xb = X + (size_t)b*CH*AL + l;
    const float* wr = W + (size_t)o*CH;
    float acc = bias ? bias[o] : 0.0f;
    #pragma unroll 8
    for (int c=0;c<CH;++c) acc = fmaf(wr[c], xb[(size_t)c*AL], acc);
    if (EPI==1) acc *= Mask[b*AL + l];
    if (EPI==4) acc *= Mask[b*AL + l] * St[((size_t)b*CH + o)*2+1] * SCALE;
    if (EPI==2) {
        const size_t oi = (size_t)b*CH*AL + (size_t)o*AL + l;
        acc = Resid[oi] + gelu_f(acc);
    }
    if (TR == 0) Out[(size_t)b*CH*AL + (size_t)o*AL + l] = acc;
    else         Out[((size_t)b*AL + l)*CH + o] = acc;
}

// ---------------------------------------------------------------------------
// lbias[b][l] = -sum_c mean_q[b][c] * Kn[b][c][l]   (Kn already has rstd*SCALE*mask)
__global__ __launch_bounds__(256)
void lbias_kernel(const float* __restrict__ Kn, const float* __restrict__ St,
                  float* __restrict__ Lb)
{
    const int b = blockIdx.x, tid = threadIdx.x;
    const int l = tid & 31, g = tid >> 5;
    float s = 0.f;
    #pragma unroll 8
    for (int cc=0; cc<32; ++cc){
        const int c = g*32 + cc;
        s += St[((size_t)b*CH + c)*2] * Kn[((size_t)b*CH + c)*AL + l];
    }
    __shared__ float red[8][32];
    red[g][l] = s;
    __syncthreads();
    if (tid < 32){
        float t = 0.f;
        #pragma unroll
        for (int gg=0; gg<8; ++gg) t += red[gg][tid];
        Lb[b*AL + tid] = -t;
    }
}

// ---------------------------------------------------------------------------
// Visual attention, 256 tokens/block. All global accesses are >=256B-contiguous
// per wave instruction (round-1's 128B windows caused ~3x HBM amplification).
// Q raw fp32 [b][c][p] (norm folded into Kn + Lb). Kn fp32 [b][c][l].
// AVt fp32 [b][l][c]. Output bf16 [b][p][c].
// LDS (80KB exactly, 2 blocks/CU):
//   R1 32KB: sKn [256 c][32 l] f32  -> overlaid by sOut [64 tok][256 c] bf16
//   R2 16KB: sPb [32 l][256 tok] bf16 probabilities
//   R3 32KB: sAV [32 l][256 c] f32
__global__ __launch_bounds__(256,2)
void attn_v_kernel(const float* __restrict__ Q, const float* __restrict__ Kn,
                   const float* __restrict__ AVt, const float* __restrict__ Lb,
                   const float* __restrict__ Mask, ushort_t* __restrict__ OutB)
{
    __shared__ float smemf[20480];                       // 80 KB
    float*    sKn  = smemf;                              // 8192 f32
    ushort_t* sOut = (ushort_t*)smemf;                   // 64*256 ushort (overlay)
    ushort_t* sPb  = (ushort_t*)(smemf + 8192);          // 32*256 ushort
    float*    sAV  = smemf + 12288;                      // 32*256 f32

    const int b  = blockIdx.y;
    const int p0 = blockIdx.x * 256;
    const int tid = threadIdx.x, lane = tid & 63, w = tid >> 6;
    const int pg = lane >> 2;       // 0..15: 4-token group within wave
    const int lq = lane & 3;        // 0..3 : 8-l slice

    // stage Kn (32 KB) and AVt (32 KB), both linear wide loads
    #pragma unroll
    for (int ii=0; ii<8; ++ii){
        const int fi = ii*256 + tid;
        *(f32x4*)&sKn[fi*4] = *(const f32x4*)(Kn + (size_t)b*CH*AL + (size_t)fi*4);
        *(f32x4*)&sAV[fi*4] = *(const f32x4*)(AVt + (size_t)b*AL*CH + (size_t)fi*4);
    }
    // per-thread bias for its 8 l's
    float bias[8];
    #pragma unroll
    for (int j=0;j<8;++j){
        const int l = lq*8 + j;
        bias[j] = Lb[b*AL + l] + 10000.f*Mask[b*AL + l] - 10000.f;
    }
    __syncthreads();

    // ---- QK^T: s[i][j] = sum_c Q[c][p0+w*64+pg*4+i] * Kn[c][lq*8+j] ----
    const float* Qb = Q + (size_t)b*CH*HW + p0 + w*64 + pg*4;
    float s[4][8] = {};
    {
        f32x4 qa[8], qb2[8];
        #pragma unroll
        for (int kk=0;kk<8;++kk) qa[kk] = *(const f32x4*)(Qb + (size_t)kk*HW);
        for (int kc = 0; kc < 32; kc += 2){
            #pragma unroll
            for (int kk=0;kk<8;++kk) qb2[kk] = *(const f32x4*)(Qb + (size_t)((kc+1)*8+kk)*HW);
            #pragma unroll
            for (int kk=0;kk<8;++kk){
                const int c = kc*8 + kk;
                const f32x4 kn0 = *(const f32x4*)&sKn[c*32 + lq*8];
                const f32x4 kn1 = *(const f32x4*)&sKn[c*32 + lq*8 + 4];
                #pragma unroll
                for (int i=0;i<4;++i){
                    s[i][0]=fmaf(qa[kk][i],kn0[0],s[i][0]); s[i][1]=fmaf(qa[kk][i],kn0[1],s[i][1]);
                    s[i][2]=fmaf(qa[kk][i],kn0[2],s[i][2]); s[i][3]=fmaf(qa[kk][i],kn0[3],s[i][3]);
                    s[i][4]=fmaf(qa[kk][i],kn1[0],s[i][4]); s[i][5]=fmaf(qa[kk][i],kn1[1],s[i][5]);
                    s[i][6]=fmaf(qa[kk][i],kn1[2],s[i][6]); s[i][7]=fmaf(qa[kk][i],kn1[3],s[i][7]);
                }
            }
            if (kc+2 < 32){
                #pragma unroll
                for (int kk=0;kk<8;++kk) qa[kk] = *(const f32x4*)(Qb + (size_t)((kc+2)*8+kk)*HW);
            }
            #pragma unroll
            for (int kk=0;kk<8;++kk){
                const int c = (kc+1)*8 + kk;
                const f32x4 kn0 = *(const f32x4*)&sKn[c*32 + lq*8];
                const f32x4 kn1 = *(const f32x4*)&sKn[c*32 + lq*8 + 4];
                #pragma unroll
                for (int i=0;i<4;++i){
                    s[i][0]=fmaf(qb2[kk][i],kn0[0],s[i][0]); s[i][1]=fmaf(qb2[kk][i],kn0[1],s[i][1]);
                    s[i][2]=fmaf(qb2[kk][i],kn0[2],s[i][2]); s[i][3]=fmaf(qb2[kk][i],kn0[3],s[i][3]);
                    s[i][4]=fmaf(qb2[kk][i],kn1[0],s[i][4]); s[i][5]=fmaf(qb2[kk][i],kn1[1],s[i][5]);
                    s[i][6]=fmaf(qb2[kk][i],kn1[2],s[i][6]); s[i][7]=fmaf(qb2[kk][i],kn1[3],s[i][7]);
                }
            }
        }
    }

    // ---- in-register softmax per token (4 lq-lanes hold the 32 l's) ----
    #pragma unroll
    for (int i=0;i<4;++i){
        #pragma unroll
        for (int j=0;j<8;++j) s[i][j] += bias[j];
        float m = s[i][0];
        #pragma unroll
        for (int j=1;j<8;++j) m = fmaxf(m, s[i][j]);
        m = fmaxf(m, __shfl_xor(m, 1));
        m = fmaxf(m, __shfl_xor(m, 2));
        float z = 0.f;
        #pragma unroll
        for (int j=0;j<8;++j){ s[i][j] = expf(s[i][j]-m); z += s[i][j]; }
        z += __shfl_xor(z, 1);
        z += __shfl_xor(z, 2);
        const float rz = 1.f/z;
        #pragma unroll
        for (int j=0;j<8;++j) s[i][j] *= rz;
    }

    // write P (bf16) to sPb [l][tok]; pack token pairs into u32 (conflict-free)
    {
        const int tok = w*64 + pg*4;
        #pragma unroll
        for (int j=0;j<8;++j){
            const int l = lq*8 + j;
            unsigned u01 = (unsigned)f2bf(s[0][j]) | ((unsigned)f2bf(s[1][j])<<16);
            unsigned u23 = (unsigned)f2bf(s[2][j]) | ((unsigned)f2bf(s[3][j])<<16);
            *(unsigned*)&sPb[l*256 + tok]     = u01;
            *(unsigned*)&sPb[l*256 + tok + 2] = u23;
        }
    }
    __syncthreads();

    // ---- PV: out[tok][c] = sum_l P[l][tok] * AVt[l][c], 4 passes of 64 tokens ----
    const int tokL = tid >> 2;      // 0..63
    const int cq   = tid & 3;       // c-quarter slice (c = ch*32 + cq*8)
    for (int t0 = 0; t0 < 4; ++t0){
        const int tok = t0*64 + tokL;
        float acc[8][8] = {};
        for (int k=0;k<32;++k){
            const float pv = bf2f(sPb[k*256 + tok]);
            #pragma unroll
            for (int ch=0;ch<8;++ch){
                const f32x4 a0 = *(const f32x4*)&sAV[k*256 + ch*32 + cq*8];
                const f32x4 a1 = *(const f32x4*)&sAV[k*256 + ch*32 + cq*8 + 4];
                acc[ch][0]=fmaf(pv,a0[0],acc[ch][0]); acc[ch][1]=fmaf(pv,a0[1],acc[ch][1]);
                acc[ch][2]=fmaf(pv,a0[2],acc[ch][2]); acc[ch][3]=fmaf(pv,a0[3],acc[ch][3]);
                acc[ch][4]=fmaf(pv,a1[0],acc[ch][4]); acc[ch][5]=fmaf(pv,a1[1],acc[ch][5]);
                acc[ch][6]=fmaf(pv,a1[2],acc[ch][6]); acc[ch][7]=fmaf(pv,a1[3],acc[ch][7]);
            }
        }
        // stage to sOut (row-XOR chunk swizzle to spread banks)
        #pragma unroll
        for (int ch=0;ch<8;++ch){
            short8 u;
            #pragma unroll
            for (int j=0;j<8;++j) u[j] = (short)f2bf(acc[ch][j]);
            const int chunk = (ch*4 + cq) ^ (tokL & 7);
            *(short8*)&sOut[tokL*256 + chunk*8] = u;
        }
        __syncthreads();
        // cooperative 512B-row stores: 2 full token rows per wave instruction
        {
            ushort_t* Ob = OutB + ((size_t)b*HW + p0 + t0*64)*CH;
            const int chunk = tid & 31;
            #pragma unroll
            for (int ss=0;ss<8;++ss){
                const int row = ss*8 + (tid>>5);
                short8 v = *(const short8*)&sOut[row*256 + ((chunk ^ (row&7))*8)];
                *(short8*)(Ob + (size_t)row*CH + chunk*8) = v;
            }
        }
        __syncthreads();
    }
}

// ---------------------------------------------------------------------------
// Audio attention, phase 1: raw scores (rstd_ak folded into sAQ; mean term
// is constant over the softmax axis p and cancels).
__global__ __launch_bounds__(256)
void sima_raw_kernel(const float* __restrict__ AQ, const float* __restrict__ AK,
                     const float* __restrict__ Mask, const float* __restrict__ St,
                     float* __restrict__ Sraw)
{
    __shared__ float sAQ[CH*AL];
    const int b = blockIdx.y;
    const int p = blockIdx.x*256 + threadIdx.x;
    const int tid = threadIdx.x;
    #pragma unroll
    for (int i=0;i<32;++i){
        const int idx = tid + 256*i;
        sAQ[idx] = AQ[(size_t)b*CH*AL + idx] * Mask[b*AL + (idx&31)] * SCALE
                 * St[((size_t)b*CH + (idx>>5))*2+1];
    }
    __syncthreads();
    float s[32];
    #pragma unroll
    for (int l=0;l<32;++l) s[l]=0.f;
    const float* akb = AK + (size_t)b*CH*HW + p;
    for (int c=0;c<CH;++c){
        const float a = akb[(size_t)c*HW];
        const float* qr = &sAQ[c*32];
        #pragma unroll
        for (int l=0;l<32;++l) s[l] = fmaf(qr[l], a, s[l]);
    }
    float* outp = Sraw + (size_t)b*AL*HW + p;
    #pragma unroll
    for (int l=0;l<32;++l) outp[(size_t)l*HW] = s[l];
}

// Phase 2: per-(b,l) softmax stats over HW.
__global__ __launch_bounds__(256)
void sima_stats_kernel(const float* __restrict__ Sraw, float2* __restrict__ Stats)
{
    const size_t base = (size_t)blockIdx.x * HW;
    const int tid = threadIdx.x;
    float v[16];
    #pragma unroll
    for (int i=0;i<4;++i){
        const float4 t = *(const float4*)(Sraw + base + tid*4 + i*1024);
        v[i*4+0]=t.x; v[i*4+1]=t.y; v[i*4+2]=t.z; v[i*4+3]=t.w;
    }
    float m = v[0];
    #pragma unroll
    for (int i=1;i<16;++i) m = fmaxf(m, v[i]);
    #pragma unroll
    for (int off=1; off<64; off<<=1) m = fmaxf(m, __shfl_xor(m, off));
    __shared__ float rm[4], rz[4];
    if ((tid&63)==0) rm[tid>>6]=m;
    __syncthreads();
    m = fmaxf(fmaxf(rm[0],rm[1]), fmaxf(rm[2],rm[3]));
    float z=0.f;
    #pragma unroll
    for (int i=0;i<16;++i) z += expf(v[i]-m);
    #pragma unroll
    for (int off=1; off<64; off<<=1) z += __shfl_xor(z, off);
    if ((tid&63)==0) rz[tid>>6]=z;
    __syncthreads();
    if (tid==0) Stats[blockIdx.x] = make_float2(m, 1.0f/(rz[0]+rz[1]+rz[2]+rz[3]));
}

// Phase 3: AO[b][c][l] = (sum_p P[l][p]*VV[b][c][p] - mean_vv[c]) * rstd_vv[c]
// (uses sum_p P = 1 to fold the InstanceNorm of VV into the epilogue).
__global__ __launch_bounds__(256)
void sima_pv_kernel(const float* __restrict__ Sraw, const float2* __restrict__ SmStats,
                    const float* __restrict__ VV, const float* __restrict__ ChSt,
                    float* __restrict__ AO)
{
    __shared__ float sA[32*33];
    __shared__ float sB[64*36];
    __shared__ float sM[32], sR[32];
    const int b  = blockIdx.x >> 2;
    const int c0 = (blockIdx.x & 3) * 64;
    const int tid = threadIdx.x;
    if (tid < 32){
        const float2 st = SmStats[b*AL + tid];
        sM[tid] = st.x; sR[tid] = st.y;
    }
    __syncthreads();
    const int lh = tid & 15;
    const int cq = tid >> 4;
    const int lr = tid >> 3, k4 = (tid & 7) * 4;
    float acc[2][4] = {{0.f,0.f,0.f,0.f},{0.f,0.f,0.f,0.f}};
    for (int p0=0; p0<HW; p0+=32){
        {
            const float4 t = *(const float4*)(Sraw + ((size_t)b*AL + lr)*HW + p0 + k4);
            const float mm = sM[lr], rr2 = sR[lr];
            sA[lr*33 + k4+0] = expf(t.x-mm)*rr2;
            sA[lr*33 + k4+1] = expf(t.y-mm)*rr2;
            sA[lr*33 + k4+2] = expf(t.z-mm)*rr2;
            sA[lr*33 + k4+3] = expf(t.w-mm)*rr2;
        }
        #pragma unroll
        for (int i=0;i<2;++i){
            const int cc = (tid>>3) + 32*i;
            *(float4*)&sB[cc*36 + k4] = *(const float4*)(VV + ((size_t)b*CH + c0 + cc)*HW + p0 + k4);
        }
        __syncthreads();
        #pragma unroll
        for (int kk=0;kk<32;++kk){
            const float a0 = sA[lh*33 + kk];
            const float a1 = sA[(lh+16)*33 + kk];
            #pragma unroll
            for (int j=0;j<4;++j){
                const float bb = sB[(cq*4+j)*36 + kk];
                acc[0][j] = fmaf(a0, bb, acc[0][j]);
                acc[1][j] = fmaf(a1, bb, acc[1][j]);
            }
        }
        __syncthreads();
    }
    #pragma unroll
    for (int j=0;j<4;++j){
        const int c = c0 + cq*4 + j;
        const float m0 = ChSt[((size_t)b*CH + c)*2];
        const float r0 = ChSt[((size_t)b*CH + c)*2+1];
        AO[((size_t)b*CH + c)*AL + lh]      = (acc[0][j]-m0)*r0;
        AO[((size_t)b*CH + c)*AL + lh + 16] = (acc[1][j]-m0)*r0;
    }
}

// ---------------------------------------------------------------------------
extern "C" void kernel_launch(void* const* d_in, const int* in_sizes, int n_in,
                              void* d_out, int out_size, void* d_ws, size_t ws_size,
                              hipStream_t stream)
{
    (void)in_sizes; (void)n_in; (void)out_size; (void)ws_size;
    const float* x     = (const float*)d_in[0];
    const float* audio = (const float*)d_in[1];
    const float* amask = (const float*)d_in[2];
    const float* vis_project_w = (const float*)d_in[3];
    const float* vis_project_b = (const float*)d_in[4];
    const float* av_w = (const float*)d_in[5];
    const float* av_b = (const float*)d_in[6];
    const float* vv_w = (const float*)d_in[7];
    const float* vv_b = (const float*)d_in[8];
    const float* vo_w = (const float*)d_in[9];
    const float* vo_b = (const float*)d_in[10];
    const float* ao_w = (const float*)d_in[11];
    const float* ao_b = (const float*)d_in[12];
    const float* vs_key_w = (const float*)d_in[13];
    const float* vs_key_b = (const float*)d_in[14];
    const float* vs_q1_w = (const float*)d_in[15];
    const float* vs_q1_b = (const float*)d_in[16];
    const float* vs_q2_w = (const float*)d_in[17];
    const float* vs_q2_b = (const float*)d_in[18];
    const float* as_key_w = (const float*)d_in[19];
    const float* as_key_b = (const float*)d_in[20];
    const float* as_q1_w = (const float*)d_in[21];
    const float* as_q1_b = (const float*)d_in[22];
    const float* as_q2_w = (const float*)d_in[23];
    const float* as_q2_b = (const float*)d_in[24];
    const float* outconv_w = (const float*)d_in[25];
    const float* outconv_b = (const float*)d_in[26];
    const float* aoc_w = (const float*)d_in[27];
    const float* aoc_b = (const float*)d_in[28];
    const float* gate_w1 = (const float*)d_in[29];
    const float* gate_w2 = (const float*)d_in[30];

    float* out_x = (float*)d_out;                 // [BT][CH][HW]
    float* out_a = out_x + (size_t)BT*CH*HW;      // [BT][CH][AL]
    float* B     = out_x;                         // fp32 scratch in d_out x-region

    const size_t BIG = (size_t)BT*CH*HW;
    ushort_t* Xt   = (ushort_t*)d_ws;             // bf16 [b][p][c], 128 MiB
    ushort_t* VISB = Xt + BIG;                    // bf16 [b][p][c], 128 MiB
    float*  A     = (float*)(VISB + BIG);         // fp32 [b][c][p], 256 MiB
    float*  SIMA  = A + BIG;                      // fp32 [b][l][p], 32 MiB
    float2* STATS = (float2*)(SIMA + (size_t)BT*AL*HW);
    float*  S0 = (float*)(STATS + BT*AL);         // AVt [b][l][c]
    float*  S1 = S0 + (size_t)BT*CH*AL;           // Kn  [b][c][l]
    float*  S2 = S1 + (size_t)BT*CH*AL;           // aq
    float*  S3 = S2 + (size_t)BT*CH*AL;           // tmp / audio_res
    float*  S4 = S3 + (size_t)BT*CH*AL;           // audio_o
    ushort_t* Wb = (ushort_t*)(S4 + (size_t)BT*CH*AL);  // 9 bf16 weights
    float*  SA = (float*)(Wb + (size_t)9*65536);  // channel stats A (q1 -> q -> vo)
    float*  SB = SA + (size_t)2*BT*CH;            // channel stats B (ak -> vv)
    float*  LB = SB + (size_t)2*BT*CH;            // attn l-bias [b][l]

    dim3 b256(256);
    dim3 gW(64, 9);
    dim3 gL(BT, CH/8);
    dim3 gT(HW/32, CH/32, BT);
    dim3 gG(HW/128, CH/128, BT);
    dim3 gAttnV(HW/256, BT);
    dim3 gSimA(HW/256, BT);
    dim3 gZ(2*BT*CH/256);
    dim3 gF(BT*CH/256);

    #define WSLOT(i) (Wb + (size_t)(i)*65536)
    // slots: 0 vs_q1, 1 as_key, 2 vv, 3 vis_project, 4 vs_q2, 5 vo, 6 outconv, 7 gate_w1, 8 gate_w2
    hipLaunchKernelGGL(wconv_kernel, gW, b256, 0, stream,
                       vs_q1_w, as_key_w, vv_w, vis_project_w, vs_q2_w, vo_w, outconv_w, gate_w1, gate_w2, Wb);
    // audio small convs
    hipLaunchKernelGGL((conv_l_kernel<1,1>), gL, b256, 0, stream, av_w, av_b, audio, S0, amask, nullptr, nullptr);
    hipLaunchKernelGGL((conv_l_kernel<0,0>), gL, b256, 0, stream, as_q1_w, as_q1_b, audio, S3, nullptr, nullptr, nullptr);
    hipLaunchKernelGGL((conv_l_kernel<0,0>), gL, b256, 0, stream, as_q2_w, as_q2_b, S3, S2, nullptr, nullptr, nullptr);
    // Xt = T(x)
    hipLaunchKernelGGL((transpose_bf16_kernel<0>), gT, b256, 0, stream, x, nullptr, nullptr, Xt);
    // q1 = conv(vs_q1, x) (raw) + stats
    hipLaunchKernelGGL(zero_kernel, gZ, b256, 0, stream, SA);
    hipLaunchKernelGGL((gemm_mfma_kernel<0,0,1>), gG, b256, 0, stream, WSLOT(0), vs_q1_b, Xt, A, nullptr, nullptr, nullptr, SA);
    hipLaunchKernelGGL(stats_finalize_kernel, gF, b256, 0, stream, SA);
    // ak = conv(as_key, x) (raw) + stats
    hipLaunchKernelGGL(zero_kernel, gZ, b256, 0, stream, SB);
    hipLaunchKernelGGL((gemm_mfma_kernel<0,0,1>), gG, b256, 0, stream, WSLOT(1), as_key_b, Xt, B, nullptr, nullptr, nullptr, SB);
    hipLaunchKernelGGL(stats_finalize_kernel, gF, b256, 0, stream, SB);
    hipLaunchKernelGGL(sima_raw_kernel, gSimA, b256, 0, stream, S2, B, amask, SB, SIMA);
    hipLaunchKernelGGL(sima_stats_kernel, dim3(BT*AL), b256, 0, stream, SIMA, STATS);
    // vv = conv(vv, x) (raw) + stats
    hipLaunchKernelGGL(zero_kernel, gZ, b256, 0, stream, SB);
    hipLaunchKernelGGL((gemm_mfma_kernel<0,0,1>), gG, b256, 0, stream, WSLOT(2), vv_b, Xt, B, nullptr, nullptr, nullptr, SB);
    hipLaunchKernelGGL(stats_finalize_kernel, gF, b256, 0, stream, SB);
    hipLaunchKernelGGL(sima_pv_kernel, dim3(BT*4), b256, 0, stream, SIMA, STATS, B, SB, S4);
    hipLaunchKernelGGL((conv_l_kernel<0,0>), gL, b256, 0, stream, ao_w, ao_b, S4, S3, nullptr, nullptr, nullptr);
    hipLaunchKernelGGL((conv_l_kernel<2,0>), gL, b256, 0, stream, aoc_w, aoc_b, S3, out_a, nullptr, audio, nullptr);
    // vis = gelu(conv(vis_project, x)) -> VISB (bf16 tokens)
    hipLaunchKernelGGL((gemm_mfma_kernel<1,1,0>), gG, b256, 0, stream, WSLOT(3), vis_project_b, Xt, nullptr, VISB, nullptr, nullptr, nullptr);
    // q1n (normalized via SA) -> Xt
    hipLaunchKernelGGL((transpose_bf16_kernel<1>), gT, b256, 0, stream, A, nullptr, SA, Xt);
    // q = conv(vs_q2, q1n) (raw) + stats
    hipLaunchKernelGGL(zero_kernel, gZ, b256, 0, stream, SA);
    hipLaunchKernelGGL((gemm_mfma_kernel<0,0,1>), gG, b256, 0, stream, WSLOT(4), vs_q2_b, Xt, B, nullptr, nullptr, nullptr, SA);
    hipLaunchKernelGGL(stats_finalize_kernel, gF, b256, 0, stream, SA);
    // Kn = conv(vs_key, audio)*mask*rstd_q*scale ; lbias from mean_q
    hipLaunchKernelGGL((conv_l_kernel<4,0>), gL, b256, 0, stream, vs_key_w, vs_key_b, audio, S1, amask, nullptr, SA);
    hipLaunchKernelGGL(lbias_kernel, dim3(BT), b256, 0, stream, S1, SA, LB);
    // attention -> bf16 tokens in Xt
    hipLaunchKernelGGL(attn_v_kernel, gAttnV, b256, 0, stream, B, S1, S0, LB, amask, Xt);
    // vis_out raw = conv(vo, attn_out) + stats
    hipLaunchKernelGGL(zero_kernel, gZ, b256, 0, stream, SA);
    hipLaunchKernelGGL((gemm_mfma_kernel<0,0,1>), gG, b256, 0, stream, WSLOT(5), vo_b, Xt, B, nullptr, nullptr, nullptr, SA);
    hipLaunchKernelGGL(stats_finalize_kernel, gF, b256, 0, stream, SA);
    // Xt = bf16(norm(vis_out) * vis)
    hipLaunchKernelGGL((transpose_bf16_kernel<2>), gT, b256, 0, stream, B, VISB, SA, Xt);
    // vis2 = gelu(conv(outconv, .)) -> A (fp32) + VISB (bf16 tokens)
    hipLaunchKernelGGL((gemm_mfma_kernel<1,2,0>), gG, b256, 0, stream, WSLOT(6), outconv_b, Xt, A, VISB, nullptr, nullptr, nullptr);
    // gate path: relu(. @ gate_w1) -> Xt (bf16 tokens)
    hipLaunchKernelGGL((gemm_mfma_kernel<2,1,0>), gG, b256, 0, stream, WSLOT(7), nullptr, VISB, nullptr, Xt, nullptr, nullptr, nullptr);
    hipLaunchKernelGGL((gemm_mfma_kernel<3,0,0>), gG, b256, 0, stream, WSLOT(8), nullptr, Xt, out_x, nullptr, x, A, nullptr);
    #undef WSLOT
}